// Round 15
// baseline (1006.682 us; speedup 1.0000x reference)
//
#include <hip/hip_runtime.h>

// ---------------------------------------------------------------------------
// HiggsAudio dual-FFN decoder layer, MI355X gfx950.
// B=2 S=2048 D=2048 H=16 HD=128 F=8192. fp32 in/out, bf16 MFMA internally.
// R15: gu8 -> m201-style quadrant-per-phase pipeline (1 half-tile stage per
//      phase, per-phase vmcnt(4), depth-3 prefetch). Everything else = R14.
// ---------------------------------------------------------------------------

#define BB 2
#define SS 2048
#define DD 2048
#define HH 16
#define HDD 128
#define FF 8192
#define TT (BB*SS)   // 4096 tokens
#define RPAD 4608    // max compacted rows (18 tiles of 256)

typedef unsigned short ushort_t;
typedef __bf16 bf16x8 __attribute__((ext_vector_type(8)));
typedef float f32x4 __attribute__((ext_vector_type(4)));

#define DEV static __device__ __forceinline__

DEV float bf2f(ushort_t u) { __bf16 b; __builtin_memcpy(&b, &u, 2); return (float)b; }
DEV ushort_t f2bf(float f) { __bf16 b = (__bf16)f; ushort_t u; __builtin_memcpy(&u, &b, 2); return u; }

DEV void gl_lds16(const ushort_t* g, ushort_t* l) {
    // async global->LDS, 16B per lane; LDS dest is wave-uniform base + lane*16
    __builtin_amdgcn_global_load_lds((const __attribute__((address_space(1))) void*)g,
                                     (__attribute__((address_space(3))) void*)l, 16, 0, 0);
}

#define BARRIER() do { asm volatile("" ::: "memory"); __builtin_amdgcn_s_barrier(); asm volatile("" ::: "memory"); } while (0)
#define LGKM0()   asm volatile("s_waitcnt lgkmcnt(0)" ::: "memory")

// ---------------------------------------------------------------------------
// prep_all: fused prologue, block-range dispatch.
//   [0, convEnd)              : weight fp32 [K][N] -> bf16 [N][K]
//   [convEnd, convEnd+512)    : packed RoPE table cstab[s*64+i] = (cos, sin)
//   [convEnd+512, +TT)        : input RMSNorm -> h_bf
//   convEnd+512+TT            : mask-normalize + stable partition
// ---------------------------------------------------------------------------
struct ConvSeg { const float* in; ushort_t* out; int K, N, cumEnd; };
struct ConvArgs { ConvSeg s[10]; };

__global__ __launch_bounds__(256) void prep_all(ConvArgs a, int convEnd,
                                                float2* __restrict__ cstab,
                                                const float* __restrict__ hs,
                                                const float* __restrict__ iln,
                                                ushort_t* __restrict__ h_bf,
                                                const unsigned char* __restrict__ raw,
                                                int* __restrict__ perm,
                                                int* __restrict__ header) {
    __shared__ float t[32][33];      // convw tile; other branches reuse as scratch
    const int bid = blockIdx.x;
    const int tid = threadIdx.x;
    if (bid < convEnd) {
        int i = 0;
        while (bid >= a.s[i].cumEnd) ++i;
        const int base = (i == 0) ? 0 : a.s[i - 1].cumEnd;
        const int local = bid - base;
        const float* __restrict__ in = a.s[i].in;
        ushort_t* __restrict__ out = a.s[i].out;
        const int K = a.s[i].K, N = a.s[i].N;
        const int ntile = N >> 5;
        const int n0 = (local % ntile) * 32, k0 = (local / ntile) * 32;
        const int tx = tid & 31, ty = tid >> 5;
#pragma unroll
        for (int j = 0; j < 4; ++j)
            t[ty + 8 * j][tx] = in[(size_t)(k0 + ty + 8 * j) * N + n0 + tx];
        __syncthreads();
#pragma unroll
        for (int j = 0; j < 4; ++j)
            out[(size_t)(n0 + ty + 8 * j) * K + k0 + tx] = f2bf(t[tx][ty + 8 * j]);
    } else if (bid < convEnd + 512) {
        const int idx = (bid - convEnd) * 256 + tid;   // < 2048*64
        const int s = idx >> 6, i = idx & 63;
        const float inv = powf(10000.0f, -(float)i * (1.0f / 64.0f));
        const float ang = (float)s * inv;
        cstab[idx] = make_float2(cosf(ang), sinf(ang));
    } else if (bid < convEnd + 512 + TT) {
        const int row = bid - convEnd - 512;
        const float4* xr = (const float4*)(hs + (size_t)row * DD);
        float4 v0 = xr[tid * 2], v1 = xr[tid * 2 + 1];
        float ss = v0.x * v0.x + v0.y * v0.y + v0.z * v0.z + v0.w * v0.w
                 + v1.x * v1.x + v1.y * v1.y + v1.z * v1.z + v1.w * v1.w;
#pragma unroll
        for (int d = 1; d < 64; d <<= 1) ss += __shfl_xor(ss, d);
        float* red = &t[0][0];
        if ((tid & 63) == 0) red[tid >> 6] = ss;
        __syncthreads();
        const float tot = red[0] + red[1] + red[2] + red[3];
        const float sc = rsqrtf(tot * (1.0f / DD) + 1e-5f);
        const float4* wr = (const float4*)iln;
        float4 w0 = wr[tid * 2], w1 = wr[tid * 2 + 1];
        ushort_t* o = h_bf + (size_t)row * DD + tid * 8;
        o[0] = f2bf(v0.x * sc * w0.x); o[1] = f2bf(v0.y * sc * w0.y);
        o[2] = f2bf(v0.z * sc * w0.z); o[3] = f2bf(v0.w * sc * w0.w);
        o[4] = f2bf(v1.x * sc * w1.x); o[5] = f2bf(v1.y * sc * w1.y);
        o[6] = f2bf(v1.z * sc * w1.z); o[7] = f2bf(v1.w * sc * w1.w);
    } else {
        // ---- mask-normalize + stable partition (single block) ----
        int* ip = (int*)&t[0][0];
        int* ct = ip;            // 256
        int* ca = ip + 256;      // 256
        int* st = ip + 512;      // 256
        int* sa = ip + 768;      // 256
        int* misc = ip + 1024;   // [0]=flag [1]=Nt [2]=Na
        if (tid == 0) misc[0] = 0;
        __syncthreads();
        int any = 0;
        for (int i = tid; i < TT; i += 256)
            if ((i & 3) != 0 && raw[i] != 0) any = 1;
        if (any) atomicOr(&misc[0], 1);
        __syncthreads();
        const int is_byte = misc[0];
        auto mget = [&](int r) -> int {
            return is_byte ? (raw[r] != 0) : (((const int*)raw)[r] != 0);
        };
        int c0 = 0, c1 = 0;
#pragma unroll
        for (int i = 0; i < 16; ++i) {
            if (mget(tid * 16 + i)) c1++; else c0++;
        }
        ct[tid] = c0; ca[tid] = c1;
        __syncthreads();
        if (tid == 0) {
            int at = 0, aa = 0;
            for (int i = 0; i < 256; ++i) {
                st[i] = at; at += ct[i];
                sa[i] = aa; aa += ca[i];
            }
            misc[1] = at; misc[2] = aa;
        }
        __syncthreads();
        const int Nt = misc[1], Na = misc[2];
        const int A0 = (Nt + 255) & ~255;
        const int live = A0 + ((Na + 255) & ~255);
        int pt = st[tid], pa = A0 + sa[tid];
#pragma unroll
        for (int i = 0; i < 16; ++i) {
            const int r = tid * 16 + i;
            if (mget(r)) perm[pa++] = r; else perm[pt++] = r;
        }
        for (int i = Nt + tid; i < A0; i += 256) perm[i] = -1;
        for (int i = A0 + Na + tid; i < RPAD; i += 256) perm[i] = -1;
        if (tid == 0) { header[0] = Nt; header[1] = A0; header[2] = Na; header[3] = live; }
    }
}

// ---------------------------------------------------------------------------
// Gathered RMSNorm into compacted rows: out[i] = rmsnorm(x[perm[i]], w_branch)
// ---------------------------------------------------------------------------
__global__ __launch_bounds__(256) void rmsnorm_gather(const float* __restrict__ x,
                                                      const float* __restrict__ wt_text,
                                                      const float* __restrict__ wt_audio,
                                                      const int* __restrict__ perm,
                                                      const int* __restrict__ header,
                                                      ushort_t* __restrict__ out) {
    const int i = blockIdx.x, tid = threadIdx.x;
    const int p = perm[i];
    ushort_t* o = out + (size_t)i * DD + tid * 8;
    if (p < 0) {
#pragma unroll
        for (int j = 0; j < 8; ++j) o[j] = 0;
        return;
    }
    const float* wt = (i < header[1]) ? wt_text : wt_audio;
    const float4* xr = (const float4*)(x + (size_t)p * DD);
    float4 v0 = xr[tid * 2], v1 = xr[tid * 2 + 1];
    float ss = v0.x * v0.x + v0.y * v0.y + v0.z * v0.z + v0.w * v0.w
             + v1.x * v1.x + v1.y * v1.y + v1.z * v1.z + v1.w * v1.w;
#pragma unroll
    for (int d = 1; d < 64; d <<= 1) ss += __shfl_xor(ss, d);
    __shared__ float red[4];
    if ((tid & 63) == 0) red[tid >> 6] = ss;
    __syncthreads();
    const float tot = red[0] + red[1] + red[2] + red[3];
    const float sc = rsqrtf(tot * (1.0f / DD) + 1e-5f);
    const float4* wr = (const float4*)wt;
    float4 w0 = wr[tid * 2], w1 = wr[tid * 2 + 1];
    o[0] = f2bf(v0.x * sc * w0.x); o[1] = f2bf(v0.y * sc * w0.y);
    o[2] = f2bf(v0.z * sc * w0.z); o[3] = f2bf(v0.w * sc * w0.w);
    o[4] = f2bf(v1.x * sc * w1.x); o[5] = f2bf(v1.y * sc * w1.y);
    o[6] = f2bf(v1.z * sc * w1.z); o[7] = f2bf(v1.w * sc * w1.w);
}

// ---------------------------------------------------------------------------
// gemm_nt8: 256(M) x 128(N) NT bf16 GEMM, gu8-family schedule (R10/R11).
// EPI 0 = QKV with RoPE fused for Q/K (smem pair-exchange); V transposed.
// EPI 1 = WO fp32 + resid.
// ---------------------------------------------------------------------------
template <int EPI>
__global__ __launch_bounds__(512, 2) void gemm_nt8(
    const ushort_t* __restrict__ A, const ushort_t* __restrict__ W,
    int K, ushort_t* __restrict__ o0, ushort_t* __restrict__ o1,
    ushort_t* __restrict__ o2, float* __restrict__ Cf,
    const float* __restrict__ resid, const float2* __restrict__ cstab) {
    const int nwg = gridDim.x * gridDim.y;
    int bid = blockIdx.y * gridDim.x + blockIdx.x;
    bid = (bid & 7) * (nwg >> 3) + (bid >> 3);   // XCD bijective (nwg%8==0)
    const int bxx = bid % gridDim.x;
    const int byy = bid / gridDim.x;
    const int m0 = byy * 256;
    int kind = 0, n0;
    const ushort_t* B;
    if (EPI == 0) {
        kind = bxx >> 4;                  // 16 n-tiles per matrix
        n0 = (bxx & 15) * 128;
        B = W + (size_t)kind * DD * DD + (size_t)n0 * K;
    } else {
        n0 = bxx * 128;
        B = W + (size_t)n0 * K;
    }
    __shared__ ushort_t smem[49152];      // 2 x (A 16384 + B 8192) elems
    const int tid = threadIdx.x;
    const int w = tid >> 6, lane = tid & 63;
    const int wm = w >> 2, wn = w & 3;
    const int f16 = lane & 15, g4 = lane >> 4;
    const int rl = tid >> 3;
    const int cc8 = (((tid & 7) ^ ((tid >> 3) & 7)) * 8);   // pre-swizzled src col
    const ushort_t* gA = A + (size_t)m0 * K;

    auto stageAq = [&](int buf, int k0, int q) {
        gl_lds16(gA + (size_t)(q * 64 + rl) * K + k0 + cc8,
                 &smem[buf * 24576 + q * 4096 + w * 512]);
    };
    auto stageB2 = [&](int buf, int k0) {
#pragma unroll
        for (int j = 0; j < 2; ++j)
            gl_lds16(B + (size_t)(j * 64 + rl) * K + k0 + cc8,
                     &smem[buf * 24576 + 16384 + j * 4096 + w * 512]);
    };

    const int aBase = (wm * 128 + f16) * 64;
    const int bBase = (wn * 32 + f16) * 64;
    int cswz[2];
    cswz[0] = ((g4 ^ (f16 & 7)) * 8);
    cswz[1] = (((4 + g4) ^ (f16 & 7)) * 8);

    f32x4 acc[8][2] = {};
    bf16x8 af[4][2], bfr[2][2];

    // prologue: tile 0 full (6), tile 1 q0,q2,B (4)
    stageAq(0, 0, 0); stageAq(0, 0, 1); stageAq(0, 0, 2); stageAq(0, 0, 3);
    stageB2(0, 0);
    stageAq(1, 64, 0); stageAq(1, 64, 2); stageB2(1, 64);
    asm volatile("s_waitcnt vmcnt(4)" ::: "memory");
    BARRIER();

    const int nt = K / 64;
    for (int t = 0; t < nt; ++t) {
        const int cur = t & 1;
        const int ab = cur * 24576, bb = cur * 24576 + 16384;
        // ---- phase A: read A q0,q2 (m0-3) + all B; stage q1,q3(t+1)
#pragma unroll
        for (int m = 0; m < 4; ++m)
#pragma unroll
            for (int ks = 0; ks < 2; ++ks)
                af[m][ks] = *(const bf16x8*)&smem[ab + aBase + m * 1024 + cswz[ks]];
#pragma unroll
        for (int np = 0; np < 2; ++np)
#pragma unroll
            for (int ks = 0; ks < 2; ++ks)
                bfr[np][ks] = *(const bf16x8*)&smem[bb + bBase + np * 1024 + cswz[ks]];
        if (t + 1 < nt) {
            stageAq(1 - cur, (t + 1) * 64, 1);
            stageAq(1 - cur, (t + 1) * 64, 3);
        }
        BARRIER();
        LGKM0();
        __builtin_amdgcn_s_setprio(1);
#pragma unroll
        for (int m = 0; m < 4; ++m)
#pragma unroll
            for (int np = 0; np < 2; ++np)
#pragma unroll
                for (int ks = 0; ks < 2; ++ks)
                    acc[m][np] = __builtin_amdgcn_mfma_f32_16x16x32_bf16(af[m][ks], bfr[np][ks], acc[m][np], 0, 0, 0);
        __builtin_amdgcn_s_setprio(0);
        BARRIER();
        // ---- phase B: read A q1,q3 (m4-7); stage q0,q2,B(t+2)
#pragma unroll
        for (int m = 0; m < 4; ++m)
#pragma unroll
            for (int ks = 0; ks < 2; ++ks)
                af[m][ks] = *(const bf16x8*)&smem[ab + aBase + (4 + m) * 1024 + cswz[ks]];
        if (t + 2 < nt) {
            stageAq(cur, (t + 2) * 64, 0);
            stageAq(cur, (t + 2) * 64, 2);
            stageB2(cur, (t + 2) * 64);
        }
        BARRIER();
        LGKM0();
        __builtin_amdgcn_s_setprio(1);
#pragma unroll
        for (int m = 0; m < 4; ++m)
#pragma unroll
            for (int np = 0; np < 2; ++np)
#pragma unroll
                for (int ks = 0; ks < 2; ++ks)
                    acc[4 + m][np] = __builtin_amdgcn_mfma_f32_16x16x32_bf16(af[m][ks], bfr[np][ks], acc[4 + m][np], 0, 0, 0);
        __builtin_amdgcn_s_setprio(0);
        if (t + 2 < nt) { asm volatile("s_waitcnt vmcnt(4)" ::: "memory"); }
        else            { asm volatile("s_waitcnt vmcnt(0)" ::: "memory"); }
        BARRIER();
    }

    // epilogue: C/D layout col = f16, row = g4*4+j
    if (EPI == 0 && kind <= 1) {
        // ---- RoPE-fused Q/K store: exchange (d, d^64) partners via smem ----
        ushort_t* outp = (kind == 0) ? o0 : o1;
        __syncthreads();
#pragma unroll
        for (int m = 0; m < 8; ++m)
#pragma unroll
            for (int np = 0; np < 2; ++np)
#pragma unroll
                for (int j = 0; j < 4; ++j)
                    smem[(wm * 128 + m * 16 + g4 * 4 + j) * 128 + wn * 32 + np * 16 + f16]
                        = f2bf(acc[m][np][j]);
        __syncthreads();
#pragma unroll
        for (int m = 0; m < 8; ++m)
#pragma unroll
            for (int j = 0; j < 4; ++j) {
                const int rloc = wm * 128 + m * 16 + g4 * 4 + j;
                const int r = m0 + rloc;
                const int s = r & (SS - 1);
#pragma unroll
                for (int np = 0; np < 2; ++np) {
                    const int d = wn * 32 + np * 16 + f16;   // [0,128) within head
                    const float2 cs = cstab[s * 64 + (d & 63)];
                    const float v = acc[m][np][j];
                    const float p = bf2f(smem[rloc * 128 + (d ^ 64)]);
                    const float out = (d < 64) ? (v * cs.x - p * cs.y)
                                               : (v * cs.x + p * cs.y);
                    outp[(size_t)r * DD + n0 + d] = f2bf(out);
                }
            }
    } else {
#pragma unroll
        for (int m = 0; m < 8; ++m)
#pragma unroll
            for (int np = 0; np < 2; ++np)
#pragma unroll
                for (int j = 0; j < 4; ++j) {
                    const int r = m0 + wm * 128 + m * 16 + g4 * 4 + j;
                    const int c = n0 + wn * 32 + np * 16 + f16;
                    const float v = acc[m][np][j];
                    if (EPI == 0) {
                        const int b = r >> 11, s = r & (SS - 1), h = c >> 7, d = c & 127;
                        o2[(((size_t)(b * HH + h) * HDD + d) << 11) + s] = f2bf(v);
                    } else {
                        const size_t idx = (size_t)r * DD + c;
                        Cf[idx] = resid[idx] + v;
                    }
                }
    }
}

// ---------------------------------------------------------------------------
// Compacted-row down projection (m97 128^2): C[perm[r]] += acc, branch by tile.
// XCD-bijective block swizzle (T1) — grid 576 % 8 == 0.
// ---------------------------------------------------------------------------
__global__ __launch_bounds__(256, 2) void gemm_down_c(
    const ushort_t* __restrict__ A, const ushort_t* __restrict__ Bt_text,
    const ushort_t* __restrict__ Bt_audio, float* __restrict__ C,
    const int* __restrict__ perm, const int* __restrict__ header) {
    const int nwg = gridDim.x * gridDim.y;
    int bid = blockIdx.y * gridDim.x + blockIdx.x;
    bid = (bid & 7) * (nwg >> 3) + (bid >> 3);   // XCD bijective
    const int m0 = (bid / gridDim.x) * 128;
    if (m0 >= header[3]) return;           // beyond live rows
    const ushort_t* Bt = (m0 >= header[1]) ? Bt_audio : Bt_text;
    __shared__ ushort_t As[128 * 32];
    __shared__ ushort_t Bs[128 * 32];
    const int tid = threadIdx.x;
    const int w = tid >> 6, lane = tid & 63;
    const int n0 = (bid % gridDim.x) * 128;
    const int wr = w >> 1, wc = w & 1;
    f32x4 acc[4][4] = {};
    const ushort_t* gA = A + (size_t)m0 * FF;
    const ushort_t* gB = Bt + (size_t)n0 * FF;
    const int c0 = tid, c1 = 256 + tid;
    const int r0 = c0 >> 2, o0 = (c0 & 3) * 8;
    const int r1 = c1 >> 2, o1 = (c1 & 3) * 8;
    ushort_t* lA0 = &As[(w * 64) * 8];
    ushort_t* lA1 = &As[(256 + w * 64) * 8];
    ushort_t* lB0 = &Bs[(w * 64) * 8];
    ushort_t* lB1 = &Bs[(256 + w * 64) * 8];
    for (int k0 = 0; k0 < FF; k0 += 32) {
        __syncthreads();
        gl_lds16(gA + (size_t)r0 * FF + k0 + o0, lA0);
        gl_lds16(gA + (size_t)r1 * FF + k0 + o1, lA1);
        gl_lds16(gB + (size_t)r0 * FF + k0 + o0, lB0);
        gl_lds16(gB + (size_t)r1 * FF + k0 + o1, lB1);
        asm volatile("s_waitcnt vmcnt(0)" ::: "memory");
        __syncthreads();
        const int ko = (lane >> 4) * 8;
        const int ra = wr * 64 + (lane & 15);
        const int rb = wc * 64 + (lane & 15);
        bf16x8 af[4], bfv[4];
#pragma unroll
        for (int mi = 0; mi < 4; ++mi) af[mi] = *(const bf16x8*)&As[(ra + mi * 16) * 32 + ko];
#pragma unroll
        for (int ni = 0; ni < 4; ++ni) bfv[ni] = *(const bf16x8*)&Bs[(rb + ni * 16) * 32 + ko];
#pragma unroll
        for (int mi = 0; mi < 4; ++mi)
#pragma unroll
            for (int ni = 0; ni < 4; ++ni)
                acc[mi][ni] = __builtin_amdgcn_mfma_f32_16x16x32_bf16(af[mi], bfv[ni], acc[mi][ni], 0, 0, 0);
    }
    const int cl = lane & 15, r4 = (lane >> 4) * 4;
#pragma unroll
    for (int mi = 0; mi < 4; ++mi)
#pragma unroll
        for (int ni = 0; ni < 4; ++ni)
#pragma unroll
            for (int j = 0; j < 4; ++j) {
                const int r = m0 + wr * 64 + mi * 16 + r4 + j;
                const int p = perm[r];
                if (p >= 0) {
                    const int c = n0 + wc * 64 + ni * 16 + cl;
                    float* q = C + (size_t)p * DD + c;
                    *q = *q + acc[mi][ni][j];
                }
            }
}

// ---------------------------------------------------------------------------
// gemm_gu8: 256 x (128g||128u) fused gate+up GEMM, m201-style quadrant
// pipeline (R15). 8 waves; phase p computes C-quadrant (mh,nh) in order
// (0,0),(0,1),(1,1),(1,0); all waves read ONLY A-half mh + B-half nh per
// phase. One half-tile staged per phase (order Ah0,Bh0,Bh1,Ah1 of t+1),
// per-phase vmcnt(4) => depth-3 (6-load) prefetch. FIFO ledger verified:
// each region retires one phase+barrier before its first read.
// T2 swizzle throughout (0 conflicts).
// ---------------------------------------------------------------------------
__global__ __launch_bounds__(512, 2) void gemm_gu8(
    const ushort_t* __restrict__ A,
    const ushort_t* __restrict__ Bg_t, const ushort_t* __restrict__ Bu_t,
    const ushort_t* __restrict__ Bg_a, const ushort_t* __restrict__ Bu_a,
    ushort_t* __restrict__ act, const int* __restrict__ header) {
    // XCD-bijective blockIdx swizzle (nwg = 64*18 = 1152, 1152 % 8 == 0)
    const int nwg = gridDim.x * gridDim.y;
    int bid = blockIdx.y * gridDim.x + blockIdx.x;
    bid = (bid & 7) * (nwg >> 3) + (bid >> 3);
    const int bx = bid % 64;              // 128 f-cols per block
    const int by = bid / 64;              // 256 rows per block
    const int m0 = by * 256;
    if (m0 >= header[3]) return;          // dead tile: exit before any barrier
    const bool audio = (m0 >= header[1]);
    const ushort_t* Bg = audio ? Bg_a : Bg_t;
    const ushort_t* Bu = audio ? Bu_a : Bu_t;
    const int n0g = bx * 128;

    __shared__ ushort_t smem[65536];      // 2 bufs x (A 16K elems + B 16K elems)
    const int tid = threadIdx.x;
    const int w = tid >> 6, lane = tid & 63;
    const int wm2 = w >> 2, wn4 = w & 3;  // quadrant-internal wave split
    const int f16 = lane & 15, g4 = lane >> 4;

    const int rl = tid >> 3;              // 0..63
    const int cc8 = (((tid & 7) ^ ((tid >> 3) & 7)) * 8);  // T2 inverse-swizzled source
    const int wchunk = w * 64;

    const ushort_t* gA = A + (size_t)m0 * DD;

    auto stageA_h = [&](int buf, int k0, int h) {
#pragma unroll
        for (int j = 0; j < 2; ++j) {
            const int r = h * 128 + j * 64 + rl;
            gl_lds16(gA + (size_t)r * DD + k0 + cc8,
                     &smem[buf * 32768 + h * 8192 + (j * 512 + wchunk) * 8]);
        }
    };
    auto stageB_h = [&](int buf, int k0, int h) {
#pragma unroll
        for (int j = 0; j < 2; ++j) {
            const int br = h * 128 + j * 64 + rl;
            const int ty = (br >> 4) & 1;
            const int grow = ((br >> 5) << 4) + (br & 15);
            const ushort_t* src = (ty ? Bu : Bg) + (size_t)(n0g + grow) * DD + k0 + cc8;
            gl_lds16(src, &smem[buf * 32768 + 16384 + h * 8192 + (j * 512 + wchunk) * 8]);
        }
    };

    int cswz[2];
    cswz[0] = ((g4 ^ (f16 & 7)) * 8);
    cswz[1] = (((4 + g4) ^ (f16 & 7)) * 8);

    f32x4 acc[4][4][2] = {};              // [phase/quadrant][m][n] — all static idx
    bf16x8 af[4][2], bfv[2][2];

    // prologue: Ah0+Bh0(0) resident; Bh1+Ah1(0) in flight (queue = 4 loads)
    stageA_h(0, 0, 0); stageB_h(0, 0, 0);
    asm volatile("s_waitcnt vmcnt(0)" ::: "memory");
    stageB_h(0, 0, 1); stageA_h(0, 0, 1);
    BARRIER();

    const int nt = DD / 64;  // 32
    for (int t = 0; t < nt; ++t) {
        const int buf = t & 1, obuf = buf ^ 1;
        const int ab = buf * 32768, bb = buf * 32768 + 16384;
        const int k1 = (t + 1) * 64;
        const bool pf = (t + 1) < nt;
#pragma unroll
        for (int p = 0; p < 4; ++p) {
            // quadrant: p0=(0,0) p1=(0,1) p2=(1,1) p3=(1,0)
            const int mh = (p >= 2) ? 1 : 0;
            const int nh = (p == 1 || p == 2) ? 1 : 0;
            const int aB = ab + (mh * 128 + wm2 * 64 + f16) * 64;
            const int bB = bb + (nh * 128 + wn4 * 32 + f16) * 64;
            // frag reads: region guaranteed by previous phase's wait+barrier
#pragma unroll
            for (int m = 0; m < 4; ++m)
#pragma unroll
                for (int ks = 0; ks < 2; ++ks)
                    af[m][ks] = *(const bf16x8*)&smem[aB + m * 1024 + cswz[ks]];
#pragma unroll
            for (int n = 0; n < 2; ++n)
#pragma unroll
                for (int ks = 0; ks < 2; ++ks)
                    bfv[n][ks] = *(const bf16x8*)&smem[bB + n * 1024 + cswz[ks]];
            // stage one half-tile of t+1 (order: Ah0, Bh0, Bh1, Ah1)
            if (pf) {
                if (p == 0)      stageA_h(obuf, k1, 0);
                else if (p == 1) stageB_h(obuf, k1, 0);
                else if (p == 2) stageB_h(obuf, k1, 1);
                else             stageA_h(obuf, k1, 1);
                asm volatile("s_waitcnt vmcnt(4)" ::: "memory");
            } else {
                asm volatile("s_waitcnt vmcnt(0)" ::: "memory");
            }
            BARRIER();
            LGKM0();
            __builtin_amdgcn_s_setprio(1);
#pragma unroll
            for (int m = 0; m < 4; ++m)
#pragma unroll
                for (int n = 0; n < 2; ++n)
#pragma unroll
                    for (int ks = 0; ks < 2; ++ks)
                        acc[p][m][n] = __builtin_amdgcn_mfma_f32_16x16x32_bf16(
                            af[m][ks], bfv[n][ks], acc[p][m][n], 0, 0, 0);
            __builtin_amdgcn_s_setprio(0);
            BARRIER();
        }
    }

    // epilogue: acc[p][m][0]=gate, acc[p][m][1]=up for the same f-column
#pragma unroll
    for (int p = 0; p < 4; ++p) {
        const int mh = (p >= 2) ? 1 : 0;
        const int nh = (p == 1 || p == 2) ? 1 : 0;
        const int brg = nh * 128 + wn4 * 32 + f16;   // gate B-row (bit4 = 0)
        const int f = n0g + ((brg >> 5) << 4) + (brg & 15);
#pragma unroll
        for (int m = 0; m < 4; ++m)
#pragma unroll
            for (int j = 0; j < 4; ++j) {
                const int r = m0 + mh * 128 + wm2 * 64 + m * 16 + g4 * 4 + j;
                const float g = acc[p][m][0][j], u = acc[p][m][1][j];
                act[(size_t)r * FF + f] = f2bf(g / (1.0f + __expf(-g)) * u);
            }
    }
}

// ---------------------------------------------------------------------------
// Causal flash attention, q-tile 128 (8 waves), K dbuf + V single-buffer
// (64KB LDS, 2 blocks/CU), T5 setprio, T2 swizzle, defer-max (T13). LPT.
// ---------------------------------------------------------------------------
__global__ __launch_bounds__(512, 4) void attn_k(
    const ushort_t* __restrict__ qb, const ushort_t* __restrict__ kb,
    const ushort_t* __restrict__ vt, ushort_t* __restrict__ ctx) {
    __shared__ ushort_t Ks[2][64 * 128];   // [sk][d], swizzled (32 KB)
    __shared__ ushort_t Vs[128 * 64];      // [d][sk], swizzled (16 KB, single)
    __shared__ ushort_t Pw[8][16 * 64];    // per-wave P buffer, swizzled (16 KB)
    const int tid = threadIdx.x, w = tid >> 6, lane = tid & 63;
    const int qt = gridDim.x - 1 - blockIdx.x;   // LPT order
    const int bh = blockIdx.y, b = bh >> 4, h = bh & 15;
    const int q0 = qt * 128 + w * 16;
    const int f16 = lane & 15, g4 = lane >> 4;
    bf16x8 aq[4];
    {
        const ushort_t* qr = qb + ((size_t)(b * SS + q0 + f16)) * DD + h * HDD + g4 * 8;
#pragma unroll
        for (int ko = 0; ko < 4; ++ko) aq[ko] = *(const bf16x8*)(qr + ko * 32);
    }
    auto stageK = [&](int bufi, int kt) {
        const int sk0 = kt * 64;
#pragma unroll
        for (int i = 0; i < 2; ++i) {
            const int c = i * 512 + tid;
            const int csrc = ((c & 15) ^ ((c >> 4) & 7)) * 8;   // K src col, pre-swizzled
            gl_lds16(kb + ((size_t)(b * SS + sk0 + (c >> 4))) * DD + h * HDD + csrc,
                     &Ks[bufi][(i * 512 + w * 64) * 8]);
        }
    };
    auto stageV = [&](int kt) {
        const int sk0 = kt * 64;
#pragma unroll
        for (int i = 0; i < 2; ++i) {
            const int c = i * 512 + tid;
            const int csrc = ((c & 7) ^ ((c >> 3) & 7)) * 8;    // V src col, pre-swizzled
            gl_lds16(vt + ((size_t)((b * HH + h) * HDD + (c >> 3))) * SS + sk0 + csrc,
                     &Vs[(i * 512 + w * 64) * 8]);
        }
    };
    f32x4 o[8] = {};
    float mrow[4] = {-3e38f, -3e38f, -3e38f, -3e38f};
    float lrow[4] = {};
    const int nkv = 2 * qt + 2;   // kv tiles 0 .. 2qt+1
    stageK(0, 0); stageV(0);
    asm volatile("s_waitcnt vmcnt(0)" ::: "memory");
    BARRIER();
    for (int kt = 0; kt < nkv; ++kt) {
        const int cur = kt & 1;
        const bool pf = (kt + 1 < nkv);
        if (pf) stageK(cur ^ 1, kt + 1);   // +2 outstanding
        // ---- QK^T from Ks[cur] (resident) ----
        f32x4 s[4] = {};
        __builtin_amdgcn_s_setprio(1);
#pragma unroll
        for (int ko = 0; ko < 4; ++ko)
#pragma unroll
            for (int ni = 0; ni < 4; ++ni) {
                bf16x8 bk = *(const bf16x8*)&Ks[cur][(ni * 16 + f16) * 128 + (((ko * 4 + g4) ^ (f16 & 7)) * 8)];
                s[ni] = __builtin_amdgcn_mfma_f32_16x16x32_bf16(aq[ko], bk, s[ni], 0, 0, 0);
            }
        __builtin_amdgcn_s_setprio(0);
        const float scale = 0.08838834764831843f;  // 1/sqrt(128)
#pragma unroll
        for (int ni = 0; ni < 4; ++ni)
#pragma unroll
            for (int j = 0; j < 4; ++j) {
                float v = s[ni][j] * scale;
                const int kg = kt * 64 + ni * 16 + f16;       // global kv index
                const int qg = q0 + g4 * 4 + j;               // global q index
                if (kg > qg) v = -1e30f;
                s[ni][j] = v;
            }
#pragma unroll
        for (int j = 0; j < 4; ++j) {
            float tm = fmaxf(fmaxf(s[0][j], s[1][j]), fmaxf(s[2][j], s[3][j]));
#pragma unroll
            for (int dd = 1; dd < 16; dd <<= 1) tm = fmaxf(tm, __shfl_xor(tm, dd));
            // T13 defer-max: skip rescale while tile max stays within THR=8
            if (!__all(tm <= mrow[j] + 8.0f)) {
                const float mn = fmaxf(mrow[j], tm);
                const float corr = __expf(mrow[j] - mn);
                lrow[j] *= corr;
#pragma unroll
                for (int di = 0; di < 8; ++di) o[di][j] *= corr;
                mrow[j] = mn;
            }
            float sum = 0.f;
#pragma unroll
            for (int ni = 0; ni < 4; ++ni) {
                const float p = __expf(s[ni][j] - mrow[j]);
                s[ni][j] = p;
                sum += p;
            }
#pragma unroll
            for (int dd = 1; dd < 16; dd <<= 1) sum += __shfl_xor(sum, dd);
            lrow[j] += sum;
        }
        // P write (swizzled): logical (prow = g4*4+j, pcol = ni*16+f16)
#pragma unroll
        for (int ni = 0; ni < 4; ++ni)
#pragma unroll
            for (int j = 0; j < 4; ++j) {
                const int prow = g4 * 4 + j;
                const int pcb = ni * 2 + (f16 >> 3);
                Pw[w][prow * 64 + ((pcb ^ (prow & 7)) * 8) + (f16 & 7)] = f2bf(s[ni][j]);
            }
        // ---- V(kt) residency: retire oldest 2 (V issued before this iter's K)
        if (pf) { asm volatile("s_waitcnt vmcnt(2)" ::: "memory"); }
        else    { asm volatile("s_waitcnt vmcnt(0)" ::: "memory"); }
        BARRIER();
        __builtin_amdgcn_s_setprio(1);
#pragma unroll
        for (int ks = 0; ks < 2; ++ks) {
            bf16x8 pa = *(const bf16x8*)&Pw[w][f16 * 64 + (((ks * 4 + g4) ^ (f16 & 7)) * 8)];
#pragma unroll
            for (int di = 0; di < 8; ++di) {
                bf16x8 bv = *(const bf16x8*)&Vs[(di * 16 + f16) * 64 + (((ks * 4 + g4) ^ (f16 & 7)) * 8)];
                o[di] = __builtin_amdgcn_mfma_f32_16x16x32_bf16(pa, bv, o[di], 0, 0, 0);
            }
        }
        __builtin_amdgcn_s_setprio(0);
        BARRIER();   // all PV reads of Vs done block-wide
        if (pf) {
            stageV(kt + 1);                                   // overwrite Vs (safe)
            asm volatile("s_waitcnt vmcnt(2)" ::: "memory");  // K(kt+1) resident
        }
        BARRIER();
    }
    float inv[4];
#pragma unroll
    for (int j = 0; j < 4; ++j) inv[j] = 1.0f / lrow[j];
#pragma unroll
    for (int di = 0; di < 8; ++di)
#pragma unroll
        for (int j = 0; j < 4; ++j) {
            const int r = q0 + g4 * 4 + j;
            ctx[((size_t)(b * SS + r)) * DD + h * HDD + di * 16 + f16] = f2bf(o[di][j] * inv[j]);
        }
}

// ---------------------------------------------------------------------------
extern "C" void kernel_launch(void* const* d_in, const int* in_sizes, int n_in,
                              void* d_out, int out_size, void* d_ws, size_t ws_size,
                              hipStream_t stream) {
    (void)in_sizes; (void)n_in; (void)out_size; (void)ws_size;
    const float* hs  = (const float*)d_in[0];
    const unsigned char* mask_raw = (const unsigned char*)d_in[1];
    const float* wq  = (const float*)d_in[2];
    const float* wk  = (const float*)d_in[3];
    const float* wv  = (const float*)d_in[4];
    const float* wo  = (const float*)d_in[5];
    const float* iln = (const float*)d_in[6];
    const float* pln = (const float*)d_in[7];
    const float* aln = (const float*)d_in[8];
    const float* wgt = (const float*)d_in[9];
    const float* wut = (const float*)d_in[10];
    const float* wdt = (const float*)d_in[11];
    const float* wga = (const float*)d_in[12];
    const float* wua = (const float*)d_in[13];
    const float* wda = (const float*)d_in[14];

    const size_t SZ_W1 = (size_t)DD * DD * 2;       // 8 MB
    const size_t SZ_W2 = (size_t)DD * FF * 2;       // 32 MB
    const size_t SZ_A  = (size_t)TT * DD * 2;       // 16 MB

    char* ws = (char*)d_ws;
    size_t off = 0;
    auto take = [&](size_t n) { char* p = ws + off; off += n; return p; };
    ushort_t* wq_t  = (ushort_t*)take(SZ_W1);
    ushort_t* wk_t  = (ushort_t*)take(SZ_W1);
    ushort_t* wv_t  = (ushort_t*)take(SZ_W1);
    ushort_t* wo_t  = (ushort_t*)take(SZ_W1);
    ushort_t* wg_tb = (ushort_t*)take(SZ_W2);
    ushort_t* wu_tb = (ushort_t*)take(SZ_W2);
    ushort_t* wd_tb = (ushort_t*)take(SZ_W2);
    ushort_t* wg_ab = (ushort_t*)take(SZ_W2);
    ushort_t* wu_ab = (ushort_t*)take(SZ_W2);
    ushort_t* wd_ab = (ushort_t*)take(SZ_W2);
    char* actreg = take(6 * SZ_A);                  // 96 MB region, multi-use
    float2* cstab = (float2*)take((size_t)SS * 64 * 8);
    int* perm   = (int*)take(RPAD * 4);
    int* header = (int*)take(64);

    // phase-1 overlays of actreg (attention):
    ushort_t* h_bf = (ushort_t*)(actreg);
    ushort_t* qb   = (ushort_t*)(actreg + 1 * SZ_A);
    ushort_t* kb   = (ushort_t*)(actreg + 2 * SZ_A);
    ushort_t* vt   = (ushort_t*)(actreg + 3 * SZ_A);
    ushort_t* ctx  = (ushort_t*)(actreg + 4 * SZ_A);
    // phase-2 overlays (FFN):
    ushort_t* hn_c  = (ushort_t*)(actreg);                              // RPAD x DD bf16
    ushort_t* act_c = (ushort_t*)(actreg + (size_t)RPAD * DD * 2);      // RPAD x FF bf16

    const dim3 blk(256);

    // --- fused prologue: weight convert + rope table + rmsnorm + partition ---
    ConvArgs ca;
    int cum = 0;
    auto seg = [&](int i, const float* in, ushort_t* out, int K, int N) {
        cum += (N / 32) * (K / 32);
        ca.s[i] = ConvSeg{in, out, K, N, cum};
    };
    seg(0, wq, wq_t, DD, DD);
    seg(1, wk, wk_t, DD, DD);
    seg(2, wv, wv_t, DD, DD);
    seg(3, wo, wo_t, DD, DD);
    seg(4, wgt, wg_tb, DD, FF);
    seg(5, wut, wu_tb, DD, FF);
    seg(6, wdt, wd_tb, FF, DD);
    seg(7, wga, wg_ab, DD, FF);
    seg(8, wua, wu_ab, DD, FF);
    seg(9, wda, wd_ab, FF, DD);
    prep_all<<<cum + 512 + TT + 1, blk, 0, stream>>>(ca, cum, cstab, hs, iln, h_bf,
                                                     mask_raw, perm, header);

    // --- attention block (QKV with fused RoPE) ---
    gemm_nt8<0><<<dim3(48, TT / 256), dim3(512), 0, stream>>>(
        h_bf, wq_t, DD, qb, kb, vt, nullptr, nullptr, cstab);
    attn_k<<<dim3(SS / 128, BB * HH), dim3(512), 0, stream>>>(qb, kb, vt, ctx);
    // d_out = hidden = residual + ctx @ wo
    gemm_nt8<1><<<dim3(DD / 128, TT / 256), dim3(512), 0, stream>>>(
        ctx, wo_t, DD, nullptr, nullptr, nullptr, (float*)d_out, hs, nullptr);

    // --- routed dual FFN on compacted rows ---
    rmsnorm_gather<<<RPAD, blk, 0, stream>>>((const float*)d_out, pln, aln, perm, header, hn_c);
    gemm_gu8<<<dim3(FF / 128, RPAD / 256), dim3(512), 0, stream>>>(hn_c, wg_tb, wu_tb, wg_ab, wu_ab, act_c, header);
    gemm_down_c<<<dim3(DD / 128, RPAD / 128), blk, 0, stream>>>(act_c, wd_tb, wd_ab, (float*)d_out, perm, header);
}

// Round 16
// 978.761 us; speedup vs baseline: 1.0285x; 1.0285x over previous
//
#include <hip/hip_runtime.h>

// ---------------------------------------------------------------------------
// HiggsAudio dual-FFN decoder layer, MI355X gfx950.
// B=2 S=2048 D=2048 H=16 HD=128 F=8192. fp32 in/out, bf16 MFMA internally.
// R16: revert gu8 to R14 schedule (R15 quadrant pipeline regressed 317->362).
//      Identical to R14 (best measured: 980.2 us).
// ---------------------------------------------------------------------------

#define BB 2
#define SS 2048
#define DD 2048
#define HH 16
#define HDD 128
#define FF 8192
#define TT (BB*SS)   // 4096 tokens
#define RPAD 4608    // max compacted rows (18 tiles of 256)

typedef unsigned short ushort_t;
typedef __bf16 bf16x8 __attribute__((ext_vector_type(8)));
typedef float f32x4 __attribute__((ext_vector_type(4)));

#define DEV static __device__ __forceinline__

DEV float bf2f(ushort_t u) { __bf16 b; __builtin_memcpy(&b, &u, 2); return (float)b; }
DEV ushort_t f2bf(float f) { __bf16 b = (__bf16)f; ushort_t u; __builtin_memcpy(&u, &b, 2); return u; }

DEV void gl_lds16(const ushort_t* g, ushort_t* l) {
    // async global->LDS, 16B per lane; LDS dest is wave-uniform base + lane*16
    __builtin_amdgcn_global_load_lds((const __attribute__((address_space(1))) void*)g,
                                     (__attribute__((address_space(3))) void*)l, 16, 0, 0);
}

#define BARRIER() do { asm volatile("" ::: "memory"); __builtin_amdgcn_s_barrier(); asm volatile("" ::: "memory"); } while (0)
#define LGKM0()   asm volatile("s_waitcnt lgkmcnt(0)" ::: "memory")

// ---------------------------------------------------------------------------
// prep_all: fused prologue, block-range dispatch.
//   [0, convEnd)              : weight fp32 [K][N] -> bf16 [N][K]
//   [convEnd, convEnd+512)    : packed RoPE table cstab[s*64+i] = (cos, sin)
//   [convEnd+512, +TT)        : input RMSNorm -> h_bf
//   convEnd+512+TT            : mask-normalize + stable partition
// ---------------------------------------------------------------------------
struct ConvSeg { const float* in; ushort_t* out; int K, N, cumEnd; };
struct ConvArgs { ConvSeg s[10]; };

__global__ __launch_bounds__(256) void prep_all(ConvArgs a, int convEnd,
                                                float2* __restrict__ cstab,
                                                const float* __restrict__ hs,
                                                const float* __restrict__ iln,
                                                ushort_t* __restrict__ h_bf,
                                                const unsigned char* __restrict__ raw,
                                                int* __restrict__ perm,
                                                int* __restrict__ header) {
    __shared__ float t[32][33];      // convw tile; other branches reuse as scratch
    const int bid = blockIdx.x;
    const int tid = threadIdx.x;
    if (bid < convEnd) {
        int i = 0;
        while (bid >= a.s[i].cumEnd) ++i;
        const int base = (i == 0) ? 0 : a.s[i - 1].cumEnd;
        const int local = bid - base;
        const float* __restrict__ in = a.s[i].in;
        ushort_t* __restrict__ out = a.s[i].out;
        const int K = a.s[i].K, N = a.s[i].N;
        const int ntile = N >> 5;
        const int n0 = (local % ntile) * 32, k0 = (local / ntile) * 32;
        const int tx = tid & 31, ty = tid >> 5;
#pragma unroll
        for (int j = 0; j < 4; ++j)
            t[ty + 8 * j][tx] = in[(size_t)(k0 + ty + 8 * j) * N + n0 + tx];
        __syncthreads();
#pragma unroll
        for (int j = 0; j < 4; ++j)
            out[(size_t)(n0 + ty + 8 * j) * K + k0 + tx] = f2bf(t[tx][ty + 8 * j]);
    } else if (bid < convEnd + 512) {
        const int idx = (bid - convEnd) * 256 + tid;   // < 2048*64
        const int s = idx >> 6, i = idx & 63;
        const float inv = powf(10000.0f, -(float)i * (1.0f / 64.0f));
        const float ang = (float)s * inv;
        cstab[idx] = make_float2(cosf(ang), sinf(ang));
    } else if (bid < convEnd + 512 + TT) {
        const int row = bid - convEnd - 512;
        const float4* xr = (const float4*)(hs + (size_t)row * DD);
        float4 v0 = xr[tid * 2], v1 = xr[tid * 2 + 1];
        float ss = v0.x * v0.x + v0.y * v0.y + v0.z * v0.z + v0.w * v0.w
                 + v1.x * v1.x + v1.y * v1.y + v1.z * v1.z + v1.w * v1.w;
#pragma unroll
        for (int d = 1; d < 64; d <<= 1) ss += __shfl_xor(ss, d);
        float* red = &t[0][0];
        if ((tid & 63) == 0) red[tid >> 6] = ss;
        __syncthreads();
        const float tot = red[0] + red[1] + red[2] + red[3];
        const float sc = rsqrtf(tot * (1.0f / DD) + 1e-5f);
        const float4* wr = (const float4*)iln;
        float4 w0 = wr[tid * 2], w1 = wr[tid * 2 + 1];
        ushort_t* o = h_bf + (size_t)row * DD + tid * 8;
        o[0] = f2bf(v0.x * sc * w0.x); o[1] = f2bf(v0.y * sc * w0.y);
        o[2] = f2bf(v0.z * sc * w0.z); o[3] = f2bf(v0.w * sc * w0.w);
        o[4] = f2bf(v1.x * sc * w1.x); o[5] = f2bf(v1.y * sc * w1.y);
        o[6] = f2bf(v1.z * sc * w1.z); o[7] = f2bf(v1.w * sc * w1.w);
    } else {
        // ---- mask-normalize + stable partition (single block) ----
        int* ip = (int*)&t[0][0];
        int* ct = ip;            // 256
        int* ca = ip + 256;      // 256
        int* st = ip + 512;      // 256
        int* sa = ip + 768;      // 256
        int* misc = ip + 1024;   // [0]=flag [1]=Nt [2]=Na
        if (tid == 0) misc[0] = 0;
        __syncthreads();
        int any = 0;
        for (int i = tid; i < TT; i += 256)
            if ((i & 3) != 0 && raw[i] != 0) any = 1;
        if (any) atomicOr(&misc[0], 1);
        __syncthreads();
        const int is_byte = misc[0];
        auto mget = [&](int r) -> int {
            return is_byte ? (raw[r] != 0) : (((const int*)raw)[r] != 0);
        };
        int c0 = 0, c1 = 0;
#pragma unroll
        for (int i = 0; i < 16; ++i) {
            if (mget(tid * 16 + i)) c1++; else c0++;
        }
        ct[tid] = c0; ca[tid] = c1;
        __syncthreads();
        if (tid == 0) {
            int at = 0, aa = 0;
            for (int i = 0; i < 256; ++i) {
                st[i] = at; at += ct[i];
                sa[i] = aa; aa += ca[i];
            }
            misc[1] = at; misc[2] = aa;
        }
        __syncthreads();
        const int Nt = misc[1], Na = misc[2];
        const int A0 = (Nt + 255) & ~255;
        const int live = A0 + ((Na + 255) & ~255);
        int pt = st[tid], pa = A0 + sa[tid];
#pragma unroll
        for (int i = 0; i < 16; ++i) {
            const int r = tid * 16 + i;
            if (mget(r)) perm[pa++] = r; else perm[pt++] = r;
        }
        for (int i = Nt + tid; i < A0; i += 256) perm[i] = -1;
        for (int i = A0 + Na + tid; i < RPAD; i += 256) perm[i] = -1;
        if (tid == 0) { header[0] = Nt; header[1] = A0; header[2] = Na; header[3] = live; }
    }
}

// ---------------------------------------------------------------------------
// Gathered RMSNorm into compacted rows: out[i] = rmsnorm(x[perm[i]], w_branch)
// ---------------------------------------------------------------------------
__global__ __launch_bounds__(256) void rmsnorm_gather(const float* __restrict__ x,
                                                      const float* __restrict__ wt_text,
                                                      const float* __restrict__ wt_audio,
                                                      const int* __restrict__ perm,
                                                      const int* __restrict__ header,
                                                      ushort_t* __restrict__ out) {
    const int i = blockIdx.x, tid = threadIdx.x;
    const int p = perm[i];
    ushort_t* o = out + (size_t)i * DD + tid * 8;
    if (p < 0) {
#pragma unroll
        for (int j = 0; j < 8; ++j) o[j] = 0;
        return;
    }
    const float* wt = (i < header[1]) ? wt_text : wt_audio;
    const float4* xr = (const float4*)(x + (size_t)p * DD);
    float4 v0 = xr[tid * 2], v1 = xr[tid * 2 + 1];
    float ss = v0.x * v0.x + v0.y * v0.y + v0.z * v0.z + v0.w * v0.w
             + v1.x * v1.x + v1.y * v1.y + v1.z * v1.z + v1.w * v1.w;
#pragma unroll
    for (int d = 1; d < 64; d <<= 1) ss += __shfl_xor(ss, d);
    __shared__ float red[4];
    if ((tid & 63) == 0) red[tid >> 6] = ss;
    __syncthreads();
    const float tot = red[0] + red[1] + red[2] + red[3];
    const float sc = rsqrtf(tot * (1.0f / DD) + 1e-5f);
    const float4* wr = (const float4*)wt;
    float4 w0 = wr[tid * 2], w1 = wr[tid * 2 + 1];
    o[0] = f2bf(v0.x * sc * w0.x); o[1] = f2bf(v0.y * sc * w0.y);
    o[2] = f2bf(v0.z * sc * w0.z); o[3] = f2bf(v0.w * sc * w0.w);
    o[4] = f2bf(v1.x * sc * w1.x); o[5] = f2bf(v1.y * sc * w1.y);
    o[6] = f2bf(v1.z * sc * w1.z); o[7] = f2bf(v1.w * sc * w1.w);
}

// ---------------------------------------------------------------------------
// gemm_nt8: 256(M) x 128(N) NT bf16 GEMM, gu8-family schedule (R10/R11).
// EPI 0 = QKV with RoPE fused for Q/K (smem pair-exchange); V transposed.
// EPI 1 = WO fp32 + resid.
// ---------------------------------------------------------------------------
template <int EPI>
__global__ __launch_bounds__(512, 2) void gemm_nt8(
    const ushort_t* __restrict__ A, const ushort_t* __restrict__ W,
    int K, ushort_t* __restrict__ o0, ushort_t* __restrict__ o1,
    ushort_t* __restrict__ o2, float* __restrict__ Cf,
    const float* __restrict__ resid, const float2* __restrict__ cstab) {
    const int nwg = gridDim.x * gridDim.y;
    int bid = blockIdx.y * gridDim.x + blockIdx.x;
    bid = (bid & 7) * (nwg >> 3) + (bid >> 3);   // XCD bijective (nwg%8==0)
    const int bxx = bid % gridDim.x;
    const int byy = bid / gridDim.x;
    const int m0 = byy * 256;
    int kind = 0, n0;
    const ushort_t* B;
    if (EPI == 0) {
        kind = bxx >> 4;                  // 16 n-tiles per matrix
        n0 = (bxx & 15) * 128;
        B = W + (size_t)kind * DD * DD + (size_t)n0 * K;
    } else {
        n0 = bxx * 128;
        B = W + (size_t)n0 * K;
    }
    __shared__ ushort_t smem[49152];      // 2 x (A 16384 + B 8192) elems
    const int tid = threadIdx.x;
    const int w = tid >> 6, lane = tid & 63;
    const int wm = w >> 2, wn = w & 3;
    const int f16 = lane & 15, g4 = lane >> 4;
    const int rl = tid >> 3;
    const int cc8 = (((tid & 7) ^ ((tid >> 3) & 7)) * 8);   // pre-swizzled src col
    const ushort_t* gA = A + (size_t)m0 * K;

    auto stageAq = [&](int buf, int k0, int q) {
        gl_lds16(gA + (size_t)(q * 64 + rl) * K + k0 + cc8,
                 &smem[buf * 24576 + q * 4096 + w * 512]);
    };
    auto stageB2 = [&](int buf, int k0) {
#pragma unroll
        for (int j = 0; j < 2; ++j)
            gl_lds16(B + (size_t)(j * 64 + rl) * K + k0 + cc8,
                     &smem[buf * 24576 + 16384 + j * 4096 + w * 512]);
    };

    const int aBase = (wm * 128 + f16) * 64;
    const int bBase = (wn * 32 + f16) * 64;
    int cswz[2];
    cswz[0] = ((g4 ^ (f16 & 7)) * 8);
    cswz[1] = (((4 + g4) ^ (f16 & 7)) * 8);

    f32x4 acc[8][2] = {};
    bf16x8 af[4][2], bfr[2][2];

    // prologue: tile 0 full (6), tile 1 q0,q2,B (4)
    stageAq(0, 0, 0); stageAq(0, 0, 1); stageAq(0, 0, 2); stageAq(0, 0, 3);
    stageB2(0, 0);
    stageAq(1, 64, 0); stageAq(1, 64, 2); stageB2(1, 64);
    asm volatile("s_waitcnt vmcnt(4)" ::: "memory");
    BARRIER();

    const int nt = K / 64;
    for (int t = 0; t < nt; ++t) {
        const int cur = t & 1;
        const int ab = cur * 24576, bb = cur * 24576 + 16384;
        // ---- phase A: read A q0,q2 (m0-3) + all B; stage q1,q3(t+1)
#pragma unroll
        for (int m = 0; m < 4; ++m)
#pragma unroll
            for (int ks = 0; ks < 2; ++ks)
                af[m][ks] = *(const bf16x8*)&smem[ab + aBase + m * 1024 + cswz[ks]];
#pragma unroll
        for (int np = 0; np < 2; ++np)
#pragma unroll
            for (int ks = 0; ks < 2; ++ks)
                bfr[np][ks] = *(const bf16x8*)&smem[bb + bBase + np * 1024 + cswz[ks]];
        if (t + 1 < nt) {
            stageAq(1 - cur, (t + 1) * 64, 1);
            stageAq(1 - cur, (t + 1) * 64, 3);
        }
        BARRIER();
        LGKM0();
        __builtin_amdgcn_s_setprio(1);
#pragma unroll
        for (int m = 0; m < 4; ++m)
#pragma unroll
            for (int np = 0; np < 2; ++np)
#pragma unroll
                for (int ks = 0; ks < 2; ++ks)
                    acc[m][np] = __builtin_amdgcn_mfma_f32_16x16x32_bf16(af[m][ks], bfr[np][ks], acc[m][np], 0, 0, 0);
        __builtin_amdgcn_s_setprio(0);
        BARRIER();
        // ---- phase B: read A q1,q3 (m4-7); stage q0,q2,B(t+2)
#pragma unroll
        for (int m = 0; m < 4; ++m)
#pragma unroll
            for (int ks = 0; ks < 2; ++ks)
                af[m][ks] = *(const bf16x8*)&smem[ab + aBase + (4 + m) * 1024 + cswz[ks]];
        if (t + 2 < nt) {
            stageAq(cur, (t + 2) * 64, 0);
            stageAq(cur, (t + 2) * 64, 2);
            stageB2(cur, (t + 2) * 64);
        }
        BARRIER();
        LGKM0();
        __builtin_amdgcn_s_setprio(1);
#pragma unroll
        for (int m = 0; m < 4; ++m)
#pragma unroll
            for (int np = 0; np < 2; ++np)
#pragma unroll
                for (int ks = 0; ks < 2; ++ks)
                    acc[4 + m][np] = __builtin_amdgcn_mfma_f32_16x16x32_bf16(af[m][ks], bfr[np][ks], acc[4 + m][np], 0, 0, 0);
        __builtin_amdgcn_s_setprio(0);
        if (t + 2 < nt) { asm volatile("s_waitcnt vmcnt(4)" ::: "memory"); }
        else            { asm volatile("s_waitcnt vmcnt(0)" ::: "memory"); }
        BARRIER();
    }

    // epilogue: C/D layout col = f16, row = g4*4+j
    if (EPI == 0 && kind <= 1) {
        // ---- RoPE-fused Q/K store: exchange (d, d^64) partners via smem ----
        ushort_t* outp = (kind == 0) ? o0 : o1;
        __syncthreads();
#pragma unroll
        for (int m = 0; m < 8; ++m)
#pragma unroll
            for (int np = 0; np < 2; ++np)
#pragma unroll
                for (int j = 0; j < 4; ++j)
                    smem[(wm * 128 + m * 16 + g4 * 4 + j) * 128 + wn * 32 + np * 16 + f16]
                        = f2bf(acc[m][np][j]);
        __syncthreads();
#pragma unroll
        for (int m = 0; m < 8; ++m)
#pragma unroll
            for (int j = 0; j < 4; ++j) {
                const int rloc = wm * 128 + m * 16 + g4 * 4 + j;
                const int r = m0 + rloc;
                const int s = r & (SS - 1);
#pragma unroll
                for (int np = 0; np < 2; ++np) {
                    const int d = wn * 32 + np * 16 + f16;   // [0,128) within head
                    const float2 cs = cstab[s * 64 + (d & 63)];
                    const float v = acc[m][np][j];
                    const float p = bf2f(smem[rloc * 128 + (d ^ 64)]);
                    const float out = (d < 64) ? (v * cs.x - p * cs.y)
                                               : (v * cs.x + p * cs.y);
                    outp[(size_t)r * DD + n0 + d] = f2bf(out);
                }
            }
    } else {
#pragma unroll
        for (int m = 0; m < 8; ++m)
#pragma unroll
            for (int np = 0; np < 2; ++np)
#pragma unroll
                for (int j = 0; j < 4; ++j) {
                    const int r = m0 + wm * 128 + m * 16 + g4 * 4 + j;
                    const int c = n0 + wn * 32 + np * 16 + f16;
                    const float v = acc[m][np][j];
                    if (EPI == 0) {
                        const int b = r >> 11, s = r & (SS - 1), h = c >> 7, d = c & 127;
                        o2[(((size_t)(b * HH + h) * HDD + d) << 11) + s] = f2bf(v);
                    } else {
                        const size_t idx = (size_t)r * DD + c;
                        Cf[idx] = resid[idx] + v;
                    }
                }
    }
}

// ---------------------------------------------------------------------------
// Compacted-row down projection (m97 128^2): C[perm[r]] += acc, branch by tile.
// XCD-bijective block swizzle (T1) — grid 576 % 8 == 0.
// ---------------------------------------------------------------------------
__global__ __launch_bounds__(256, 2) void gemm_down_c(
    const ushort_t* __restrict__ A, const ushort_t* __restrict__ Bt_text,
    const ushort_t* __restrict__ Bt_audio, float* __restrict__ C,
    const int* __restrict__ perm, const int* __restrict__ header) {
    const int nwg = gridDim.x * gridDim.y;
    int bid = blockIdx.y * gridDim.x + blockIdx.x;
    bid = (bid & 7) * (nwg >> 3) + (bid >> 3);   // XCD bijective
    const int m0 = (bid / gridDim.x) * 128;
    if (m0 >= header[3]) return;           // beyond live rows
    const ushort_t* Bt = (m0 >= header[1]) ? Bt_audio : Bt_text;
    __shared__ ushort_t As[128 * 32];
    __shared__ ushort_t Bs[128 * 32];
    const int tid = threadIdx.x;
    const int w = tid >> 6, lane = tid & 63;
    const int n0 = (bid % gridDim.x) * 128;
    const int wr = w >> 1, wc = w & 1;
    f32x4 acc[4][4] = {};
    const ushort_t* gA = A + (size_t)m0 * FF;
    const ushort_t* gB = Bt + (size_t)n0 * FF;
    const int c0 = tid, c1 = 256 + tid;
    const int r0 = c0 >> 2, o0 = (c0 & 3) * 8;
    const int r1 = c1 >> 2, o1 = (c1 & 3) * 8;
    ushort_t* lA0 = &As[(w * 64) * 8];
    ushort_t* lA1 = &As[(256 + w * 64) * 8];
    ushort_t* lB0 = &Bs[(w * 64) * 8];
    ushort_t* lB1 = &Bs[(256 + w * 64) * 8];
    for (int k0 = 0; k0 < FF; k0 += 32) {
        __syncthreads();
        gl_lds16(gA + (size_t)r0 * FF + k0 + o0, lA0);
        gl_lds16(gA + (size_t)r1 * FF + k0 + o1, lA1);
        gl_lds16(gB + (size_t)r0 * FF + k0 + o0, lB0);
        gl_lds16(gB + (size_t)r1 * FF + k0 + o1, lB1);
        asm volatile("s_waitcnt vmcnt(0)" ::: "memory");
        __syncthreads();
        const int ko = (lane >> 4) * 8;
        const int ra = wr * 64 + (lane & 15);
        const int rb = wc * 64 + (lane & 15);
        bf16x8 af[4], bfv[4];
#pragma unroll
        for (int mi = 0; mi < 4; ++mi) af[mi] = *(const bf16x8*)&As[(ra + mi * 16) * 32 + ko];
#pragma unroll
        for (int ni = 0; ni < 4; ++ni) bfv[ni] = *(const bf16x8*)&Bs[(rb + ni * 16) * 32 + ko];
#pragma unroll
        for (int mi = 0; mi < 4; ++mi)
#pragma unroll
            for (int ni = 0; ni < 4; ++ni)
                acc[mi][ni] = __builtin_amdgcn_mfma_f32_16x16x32_bf16(af[mi], bfv[ni], acc[mi][ni], 0, 0, 0);
    }
    const int cl = lane & 15, r4 = (lane >> 4) * 4;
#pragma unroll
    for (int mi = 0; mi < 4; ++mi)
#pragma unroll
        for (int ni = 0; ni < 4; ++ni)
#pragma unroll
            for (int j = 0; j < 4; ++j) {
                const int r = m0 + wr * 64 + mi * 16 + r4 + j;
                const int p = perm[r];
                if (p >= 0) {
                    const int c = n0 + wc * 64 + ni * 16 + cl;
                    float* q = C + (size_t)p * DD + c;
                    *q = *q + acc[mi][ni][j];
                }
            }
}

// ---------------------------------------------------------------------------
// 8-phase 256x(128g||128u) fused gate+up GEMM (T2+T3+T4+T5), R11 staging.
// (R14 schedule — best measured: 317 us, MfmaUtil 40%.)
// ---------------------------------------------------------------------------
__global__ __launch_bounds__(512, 2) void gemm_gu8(
    const ushort_t* __restrict__ A,
    const ushort_t* __restrict__ Bg_t, const ushort_t* __restrict__ Bu_t,
    const ushort_t* __restrict__ Bg_a, const ushort_t* __restrict__ Bu_a,
    ushort_t* __restrict__ act, const int* __restrict__ header) {
    // XCD-bijective blockIdx swizzle (nwg = 64*18 = 1152, 1152 % 8 == 0)
    const int nwg = gridDim.x * gridDim.y;
    int bid = blockIdx.y * gridDim.x + blockIdx.x;
    bid = (bid & 7) * (nwg >> 3) + (bid >> 3);
    const int bx = bid % 64;              // 128 f-cols per block
    const int by = bid / 64;              // 256 rows per block
    const int m0 = by * 256;
    if (m0 >= header[3]) return;          // dead tile: exit before any barrier
    const bool audio = (m0 >= header[1]);
    const ushort_t* Bg = audio ? Bg_a : Bg_t;
    const ushort_t* Bu = audio ? Bu_a : Bu_t;
    const int n0g = bx * 128;

    __shared__ ushort_t smem[65536];      // 2 bufs x (A 16K elems + B 16K elems)
    const int tid = threadIdx.x;
    const int w = tid >> 6, lane = tid & 63;
    const int wm = w >> 2, wn = w & 3;
    const int f16 = lane & 15, g4 = lane >> 4;

    const int rl = tid >> 3;              // 0..63
    const int cc8 = (((tid & 7) ^ ((tid >> 3) & 7)) * 8);  // T2 inverse-swizzled source
    const int wchunk = w * 64;

    const ushort_t* gA = A + (size_t)m0 * DD;

    auto stageA_h = [&](int buf, int k0, int h) {
#pragma unroll
        for (int j = 0; j < 2; ++j) {
            const int r = h * 128 + j * 64 + rl;
            gl_lds16(gA + (size_t)r * DD + k0 + cc8,
                     &smem[buf * 32768 + h * 8192 + (j * 512 + wchunk) * 8]);
        }
    };
    auto stageB_h = [&](int buf, int k0, int h) {
#pragma unroll
        for (int j = 0; j < 2; ++j) {
            const int br = h * 128 + j * 64 + rl;
            const int ty = (br >> 4) & 1;
            const int grow = ((br >> 5) << 4) + (br & 15);
            const ushort_t* src = (ty ? Bu : Bg) + (size_t)(n0g + grow) * DD + k0 + cc8;
            gl_lds16(src, &smem[buf * 32768 + 16384 + h * 8192 + (j * 512 + wchunk) * 8]);
        }
    };

    const int aBase = (wm * 128 + f16) * 64;
    const int bBase = (wn * 64 + f16) * 64;
    int cswz[2];
    cswz[0] = ((g4 ^ (f16 & 7)) * 8);
    cswz[1] = (((4 + g4) ^ (f16 & 7)) * 8);

    f32x4 acc[8][4] = {};
    bf16x8 af[4][2], b0[2][2], b1[2][2];

    // prologue: tile 0 full; tile 1 first halves (Ah0, Bh0)
    stageA_h(0, 0, 0); stageA_h(0, 0, 1);
    stageB_h(0, 0, 0); stageB_h(0, 0, 1);
    stageA_h(1, 64, 0); stageB_h(1, 64, 0);
    asm volatile("s_waitcnt vmcnt(4)" ::: "memory");
    BARRIER();

    const int nt = DD / 64;  // 32
    for (int t = 0; t < nt; ++t) {
        const int buf = t & 1, obuf = buf ^ 1;
        const int ab = buf * 32768, bb = buf * 32768 + 16384;
        const int k1 = (t + 1) * 64, k2 = (t + 2) * 64;
        const bool pf1 = (t + 1) < nt, pf2 = (t + 2) < nt;
        // ---- phase 1: read A0+B0; stage Ah1(t+1); MFMA m0-3 x n0-1
#pragma unroll
        for (int m = 0; m < 4; ++m)
#pragma unroll
            for (int ks = 0; ks < 2; ++ks)
                af[m][ks] = *(const bf16x8*)&smem[ab + aBase + m * 1024 + cswz[ks]];
#pragma unroll
        for (int n = 0; n < 2; ++n)
#pragma unroll
            for (int ks = 0; ks < 2; ++ks)
                b0[n][ks] = *(const bf16x8*)&smem[bb + bBase + n * 1024 + cswz[ks]];
        if (pf1) stageA_h(obuf, k1, 1);
        BARRIER();
        LGKM0();
        __builtin_amdgcn_s_setprio(1);
#pragma unroll
        for (int m = 0; m < 4; ++m)
#pragma unroll
            for (int n = 0; n < 2; ++n)
#pragma unroll
                for (int ks = 0; ks < 2; ++ks)
                    acc[m][n] = __builtin_amdgcn_mfma_f32_16x16x32_bf16(af[m][ks], b0[n][ks], acc[m][n], 0, 0, 0);
        __builtin_amdgcn_s_setprio(0);
        BARRIER();
        // ---- phase 2: read B1; stage Bh1(t+1); MFMA m0-3 x n2-3
#pragma unroll
        for (int n = 0; n < 2; ++n)
#pragma unroll
            for (int ks = 0; ks < 2; ++ks)
                b1[n][ks] = *(const bf16x8*)&smem[bb + bBase + (2 + n) * 1024 + cswz[ks]];
        if (pf1) stageB_h(obuf, k1, 1);
        BARRIER();
        LGKM0();
        __builtin_amdgcn_s_setprio(1);
#pragma unroll
        for (int m = 0; m < 4; ++m)
#pragma unroll
            for (int n = 0; n < 2; ++n)
#pragma unroll
                for (int ks = 0; ks < 2; ++ks)
                    acc[m][2 + n] = __builtin_amdgcn_mfma_f32_16x16x32_bf16(af[m][ks], b1[n][ks], acc[m][2 + n], 0, 0, 0);
        __builtin_amdgcn_s_setprio(0);
        BARRIER();
        // ---- phase 3: read A1; stage Bh0(t+2); MFMA m4-7 x n0-1
#pragma unroll
        for (int m = 0; m < 4; ++m)
#pragma unroll
            for (int ks = 0; ks < 2; ++ks)
                af[m][ks] = *(const bf16x8*)&smem[ab + aBase + (4 + m) * 1024 + cswz[ks]];
        if (pf2) stageB_h(buf, k2, 0);
        BARRIER();
        LGKM0();
        __builtin_amdgcn_s_setprio(1);
#pragma unroll
        for (int m = 0; m < 4; ++m)
#pragma unroll
            for (int n = 0; n < 2; ++n)
#pragma unroll
                for (int ks = 0; ks < 2; ++ks)
                    acc[4 + m][n] = __builtin_amdgcn_mfma_f32_16x16x32_bf16(af[m][ks], b0[n][ks], acc[4 + m][n], 0, 0, 0);
        __builtin_amdgcn_s_setprio(0);
        BARRIER();
        // ---- phase 4: stage Ah0(t+2); MFMA m4-7 x n2-3; counted vmcnt
        if (pf2) stageA_h(buf, k2, 0);
        BARRIER();
        __builtin_amdgcn_s_setprio(1);
#pragma unroll
        for (int m = 0; m < 4; ++m)
#pragma unroll
            for (int n = 0; n < 2; ++n)
#pragma unroll
                for (int ks = 0; ks < 2; ++ks)
                    acc[4 + m][2 + n] = __builtin_amdgcn_mfma_f32_16x16x32_bf16(af[m][ks], b1[n][ks], acc[4 + m][2 + n], 0, 0, 0);
        __builtin_amdgcn_s_setprio(0);
        if (pf2)      { asm volatile("s_waitcnt vmcnt(4)" ::: "memory"); }
        else if (pf1) { asm volatile("s_waitcnt vmcnt(0)" ::: "memory"); }
        BARRIER();
    }

    // epilogue: acc[m][even]=gate, acc[m][odd]=up for the same f-column
    const int r4 = g4 * 4;
#pragma unroll
    for (int m = 0; m < 8; ++m)
#pragma unroll
        for (int np = 0; np < 2; ++np) {
            const int f = n0g + (wn * 2 + np) * 16 + f16;
#pragma unroll
            for (int j = 0; j < 4; ++j) {
                const int r = m0 + wm * 128 + m * 16 + r4 + j;
                const float g = acc[m][np * 2][j], u = acc[m][np * 2 + 1][j];
                act[(size_t)r * FF + f] = f2bf(g / (1.0f + __expf(-g)) * u);
            }
        }
}

// ---------------------------------------------------------------------------
// Causal flash attention, q-tile 128 (8 waves), K dbuf + V single-buffer
// (64KB LDS, 2 blocks/CU), T5 setprio, T2 swizzle, defer-max (T13). LPT.
// ---------------------------------------------------------------------------
__global__ __launch_bounds__(512, 4) void attn_k(
    const ushort_t* __restrict__ qb, const ushort_t* __restrict__ kb,
    const ushort_t* __restrict__ vt, ushort_t* __restrict__ ctx) {
    __shared__ ushort_t Ks[2][64 * 128];   // [sk][d], swizzled (32 KB)
    __shared__ ushort_t Vs[128 * 64];      // [d][sk], swizzled (16 KB, single)
    __shared__ ushort_t Pw[8][16 * 64];    // per-wave P buffer, swizzled (16 KB)
    const int tid = threadIdx.x, w = tid >> 6, lane = tid & 63;
    const int qt = gridDim.x - 1 - blockIdx.x;   // LPT order
    const int bh = blockIdx.y, b = bh >> 4, h = bh & 15;
    const int q0 = qt * 128 + w * 16;
    const int f16 = lane & 15, g4 = lane >> 4;
    bf16x8 aq[4];
    {
        const ushort_t* qr = qb + ((size_t)(b * SS + q0 + f16)) * DD + h * HDD + g4 * 8;
#pragma unroll
        for (int ko = 0; ko < 4; ++ko) aq[ko] = *(const bf16x8*)(qr + ko * 32);
    }
    auto stageK = [&](int bufi, int kt) {
        const int sk0 = kt * 64;
#pragma unroll
        for (int i = 0; i < 2; ++i) {
            const int c = i * 512 + tid;
            const int csrc = ((c & 15) ^ ((c >> 4) & 7)) * 8;   // K src col, pre-swizzled
            gl_lds16(kb + ((size_t)(b * SS + sk0 + (c >> 4))) * DD + h * HDD + csrc,
                     &Ks[bufi][(i * 512 + w * 64) * 8]);
        }
    };
    auto stageV = [&](int kt) {
        const int sk0 = kt * 64;
#pragma unroll
        for (int i = 0; i < 2; ++i) {
            const int c = i * 512 + tid;
            const int csrc = ((c & 7) ^ ((c >> 3) & 7)) * 8;    // V src col, pre-swizzled
            gl_lds16(vt + ((size_t)((b * HH + h) * HDD + (c >> 3))) * SS + sk0 + csrc,
                     &Vs[(i * 512 + w * 64) * 8]);
        }
    };
    f32x4 o[8] = {};
    float mrow[4] = {-3e38f, -3e38f, -3e38f, -3e38f};
    float lrow[4] = {};
    const int nkv = 2 * qt + 2;   // kv tiles 0 .. 2qt+1
    stageK(0, 0); stageV(0);
    asm volatile("s_waitcnt vmcnt(0)" ::: "memory");
    BARRIER();
    for (int kt = 0; kt < nkv; ++kt) {
        const int cur = kt & 1;
        const bool pf = (kt + 1 < nkv);
        if (pf) stageK(cur ^ 1, kt + 1);   // +2 outstanding
        // ---- QK^T from Ks[cur] (resident) ----
        f32x4 s[4] = {};
        __builtin_amdgcn_s_setprio(1);
#pragma unroll
        for (int ko = 0; ko < 4; ++ko)
#pragma unroll
            for (int ni = 0; ni < 4; ++ni) {
                bf16x8 bk = *(const bf16x8*)&Ks[cur][(ni * 16 + f16) * 128 + (((ko * 4 + g4) ^ (f16 & 7)) * 8)];
                s[ni] = __builtin_amdgcn_mfma_f32_16x16x32_bf16(aq[ko], bk, s[ni], 0, 0, 0);
            }
        __builtin_amdgcn_s_setprio(0);
        const float scale = 0.08838834764831843f;  // 1/sqrt(128)
#pragma unroll
        for (int ni = 0; ni < 4; ++ni)
#pragma unroll
            for (int j = 0; j < 4; ++j) {
                float v = s[ni][j] * scale;
                const int kg = kt * 64 + ni * 16 + f16;       // global kv index
                const int qg = q0 + g4 * 4 + j;               // global q index
                if (kg > qg) v = -1e30f;
                s[ni][j] = v;
            }
#pragma unroll
        for (int j = 0; j < 4; ++j) {
            float tm = fmaxf(fmaxf(s[0][j], s[1][j]), fmaxf(s[2][j], s[3][j]));
#pragma unroll
            for (int dd = 1; dd < 16; dd <<= 1) tm = fmaxf(tm, __shfl_xor(tm, dd));
            // T13 defer-max: skip rescale while tile max stays within THR=8
            if (!__all(tm <= mrow[j] + 8.0f)) {
                const float mn = fmaxf(mrow[j], tm);
                const float corr = __expf(mrow[j] - mn);
                lrow[j] *= corr;
#pragma unroll
                for (int di = 0; di < 8; ++di) o[di][j] *= corr;
                mrow[j] = mn;
            }
            float sum = 0.f;
#pragma unroll
            for (int ni = 0; ni < 4; ++ni) {
                const float p = __expf(s[ni][j] - mrow[j]);
                s[ni][j] = p;
                sum += p;
            }
#pragma unroll
            for (int dd = 1; dd < 16; dd <<= 1) sum += __shfl_xor(sum, dd);
            lrow[j] += sum;
        }
        // P write (swizzled): logical (prow = g4*4+j, pcol = ni*16+f16)
#pragma unroll
        for (int ni = 0; ni < 4; ++ni)
#pragma unroll
            for (int j = 0; j < 4; ++j) {
                const int prow = g4 * 4 + j;
                const int pcb = ni * 2 + (f16 >> 3);
                Pw[w][prow * 64 + ((pcb ^ (prow & 7)) * 8) + (f16 & 7)] = f2bf(s[ni][j]);
            }
        // ---- V(kt) residency: retire oldest 2 (V issued before this iter's K)
        if (pf) { asm volatile("s_waitcnt vmcnt(2)" ::: "memory"); }
        else    { asm volatile("s_waitcnt vmcnt(0)" ::: "memory"); }
        BARRIER();
        __builtin_amdgcn_s_setprio(1);
#pragma unroll
        for (int ks = 0; ks < 2; ++ks) {
            bf16x8 pa = *(const bf16x8*)&Pw[w][f16 * 64 + (((ks * 4 + g4) ^ (f16 & 7)) * 8)];
#pragma unroll
            for (int di = 0; di < 8; ++di) {
                bf16x8 bv = *(const bf16x8*)&Vs[(di * 16 + f16) * 64 + (((ks * 4 + g4) ^ (f16 & 7)) * 8)];
                o[di] = __builtin_amdgcn_mfma_f32_16x16x32_bf16(pa, bv, o[di], 0, 0, 0);
            }
        }
        __builtin_amdgcn_s_setprio(0);
        BARRIER();   // all PV reads of Vs done block-wide
        if (pf) {
            stageV(kt + 1);                                   // overwrite Vs (safe)
            asm volatile("s_waitcnt vmcnt(2)" ::: "memory");  // K(kt+1) resident
        }
        BARRIER();
    }
    float inv[4];
#pragma unroll
    for (int j = 0; j < 4; ++j) inv[j] = 1.0f / lrow[j];
#pragma unroll
    for (int di = 0; di < 8; ++di)
#pragma unroll
        for (int j = 0; j < 4; ++j) {
            const int r = q0 + g4 * 4 + j;
            ctx[((size_t)(b * SS + r)) * DD + h * HDD + di * 16 + f16] = f2bf(o[di][j] * inv[j]);
        }
}

// ---------------------------------------------------------------------------
extern "C" void kernel_launch(void* const* d_in, const int* in_sizes, int n_in,
                              void* d_out, int out_size, void* d_ws, size_t ws_size,
                              hipStream_t stream) {
    (void)in_sizes; (void)n_in; (void)out_size; (void)ws_size;
    const float* hs  = (const float*)d_in[0];
    const unsigned char* mask_raw = (const unsigned char*)d_in[1];
    const float* wq  = (const float*)d_in[2];
    const float* wk  = (const float*)d_in[3];
    const float* wv  = (const float*)d_in[4];
    const float* wo  = (const float*)d_in[5];
    const float* iln = (const float*)d_in[6];
    const float* pln = (const float*)d_in[7];
    const float* aln = (const float*)d_in[8];
    const float* wgt = (const float*)d_in[9];
    const float* wut = (const float*)d_in[10];
    const float* wdt = (const float*)d_in[11];
    const float* wga = (const float*)d_in[12];
    const float* wua = (const float*)d_in[13];
    const float* wda = (const float*)d_in[14];

    const size_t SZ_W1 = (size_t)DD * DD * 2;       // 8 MB
    const size_t SZ_W2 = (size_t)DD * FF * 2;       // 32 MB
    const size_t SZ_A  = (size_t)TT * DD * 2;       // 16 MB

    char* ws = (char*)d_ws;
    size_t off = 0;
    auto take = [&](size_t n) { char* p = ws + off; off += n; return p; };
    ushort_t* wq_t  = (ushort_t*)take(SZ_W1);
    ushort_t* wk_t  = (ushort_t*)take(SZ_W1);
    ushort_t* wv_t  = (ushort_t*)take(SZ_W1);
    ushort_t* wo_t  = (ushort_t*)take(SZ_W1);
    ushort_t* wg_tb = (ushort_t*)take(SZ_W2);
    ushort_t* wu_tb = (ushort_t*)take(SZ_W2);
    ushort_t* wd_tb = (ushort_t*)take(SZ_W2);
    ushort_t* wg_ab = (ushort_t*)take(SZ_W2);
    ushort_t* wu_ab = (ushort_t*)take(SZ_W2);
    ushort_t* wd_ab = (ushort_t*)take(SZ_W2);
    char* actreg = take(6 * SZ_A);                  // 96 MB region, multi-use
    float2* cstab = (float2*)take((size_t)SS * 64 * 8);
    int* perm   = (int*)take(RPAD * 4);
    int* header = (int*)take(64);

    // phase-1 overlays of actreg (attention):
    ushort_t* h_bf = (ushort_t*)(actreg);
    ushort_t* qb   = (ushort_t*)(actreg + 1 * SZ_A);
    ushort_t* kb   = (ushort_t*)(actreg + 2 * SZ_A);
    ushort_t* vt   = (ushort_t*)(actreg + 3 * SZ_A);
    ushort_t* ctx  = (ushort_t*)(actreg + 4 * SZ_A);
    // phase-2 overlays (FFN):
    ushort_t* hn_c  = (ushort_t*)(actreg);                              // RPAD x DD bf16
    ushort_t* act_c = (ushort_t*)(actreg + (size_t)RPAD * DD * 2);      // RPAD x FF bf16

    const dim3 blk(256);

    // --- fused prologue: weight convert + rope table + rmsnorm + partition ---
    ConvArgs ca;
    int cum = 0;
    auto seg = [&](int i, const float* in, ushort_t* out, int K, int N) {
        cum += (N / 32) * (K / 32);
        ca.s[i] = ConvSeg{in, out, K, N, cum};
    };
    seg(0, wq, wq_t, DD, DD);
    seg(1, wk, wk_t, DD, DD);
    seg(2, wv, wv_t, DD, DD);
    seg(3, wo, wo_t, DD, DD);
    seg(4, wgt, wg_tb, DD, FF);
    seg(5, wut, wu_tb, DD, FF);
    seg(6, wdt, wd_tb, FF, DD);
    seg(7, wga, wg_ab, DD, FF);
    seg(8, wua, wu_ab, DD, FF);
    seg(9, wda, wd_ab, FF, DD);
    prep_all<<<cum + 512 + TT + 1, blk, 0, stream>>>(ca, cum, cstab, hs, iln, h_bf,
                                                     mask_raw, perm, header);

    // --- attention block (QKV with fused RoPE) ---
    gemm_nt8<0><<<dim3(48, TT / 256), dim3(512), 0, stream>>>(
        h_bf, wq_t, DD, qb, kb, vt, nullptr, nullptr, cstab);
    attn_k<<<dim3(SS / 128, BB * HH), dim3(512), 0, stream>>>(qb, kb, vt, ctx);
    // d_out = hidden = residual + ctx @ wo
    gemm_nt8<1><<<dim3(DD / 128, TT / 256), dim3(512), 0, stream>>>(
        ctx, wo_t, DD, nullptr, nullptr, nullptr, (float*)d_out, hs, nullptr);

    // --- routed dual FFN on compacted rows ---
    rmsnorm_gather<<<RPAD, blk, 0, stream>>>((const float*)d_out, pln, aln, perm, header, hn_c);
    gemm_gu8<<<dim3(FF / 128, RPAD / 256), dim3(512), 0, stream>>>(hn_c, wg_tb, wu_tb, wg_ab, wu_ab, act_c, header);
    gemm_down_c<<<dim3(DD / 128, RPAD / 128), blk, 0, stream>>>(act_c, wd_tb, wd_ab, (float*)d_out, perm, header);
}